// Round 1
// baseline (1260.160 us; speedup 1.0000x reference)
//
#include <hip/hip_runtime.h>

#define NN 50000
#define NE 800000
#define HH 128

static inline size_t align256(size_t x) { return (x + 255) & ~(size_t)255; }

// ---------------- degree histogram ----------------
__global__ void k_deg(const int* __restrict__ dst, int* __restrict__ deg) {
    int e = blockIdx.x * 256 + threadIdx.x;
    if (e < NE) atomicAdd(&deg[dst[e]], 1);
}

// ---------------- exclusive scan (offsets) + dinv ----------------
__global__ void k_scan(const int* __restrict__ deg, int* __restrict__ offsets,
                       float* __restrict__ dinv, int n) {
    __shared__ int sd[1024];
    __shared__ int s_carry;
    const int t = threadIdx.x;
    if (t == 0) s_carry = 0;
    __syncthreads();
    for (int base = 0; base < n; base += 1024) {
        int i = base + t;
        int v = (i < n) ? deg[i] : 0;
        sd[t] = v;
        __syncthreads();
        for (int off = 1; off < 1024; off <<= 1) {
            int add = (t >= off) ? sd[t - off] : 0;
            __syncthreads();
            sd[t] += add;
            __syncthreads();
        }
        int incl = sd[t];
        int carry = s_carry;
        if (i < n) {
            offsets[i] = carry + incl - v;
            dinv[i] = (v > 0) ? rsqrtf((float)v) : 0.0f;
        }
        __syncthreads();
        if (t == 1023) s_carry = carry + incl;
        __syncthreads();
    }
    if (t == 0) offsets[n] = s_carry;
}

// ---------------- CSR fill (sorted by dst) ----------------
__global__ void k_fill(const int* __restrict__ src, const int* __restrict__ dst,
                       const int* __restrict__ offsets, int* __restrict__ cursor,
                       const float* __restrict__ dinv,
                       int* __restrict__ csrc, float* __restrict__ cnorm) {
    int e = blockIdx.x * 256 + threadIdx.x;
    if (e >= NE) return;
    int s = src[e], d = dst[e];
    int pos = atomicAdd(&cursor[d], 1);
    int idx = offsets[d] + pos;
    csrc[idx] = s;
    cnorm[idx] = dinv[s] * dinv[d];
}

// ---------------- dense matmul: Out[n][c] = A[n][:]@W[:,c] (+bias*(deg?)) (+Cin) (relu?)
template <int HAS_BIAS, int HAS_DEG, int HAS_CIN, int RELU>
__global__ __launch_bounds__(256, 2) void k_mm(
    const float* __restrict__ A, const float* __restrict__ W,
    const float* __restrict__ bias, const int* __restrict__ deg,
    const float* __restrict__ Cin, float* __restrict__ Out, int nrows) {
    __shared__ float Wl[64 * HH];   // 32 KB (K-chunk of W)
    __shared__ float Al[32 * HH];   // 16 KB (32-row tile of A)
    const int t = threadIdx.x;
    const int row0 = blockIdx.x * 32;
    const int rows_here = min(32, nrows - row0);

    // stage A tile
    {
        const float4* Av = (const float4*)(A + (size_t)row0 * HH);
        float4* Alv = (float4*)Al;
        for (int i = t; i < 32 * (HH / 4); i += 256) {
            int r = i >> 5;  // 32 float4 per row
            float4 z = {0.f, 0.f, 0.f, 0.f};
            Alv[i] = (r < rows_here) ? Av[i] : z;
        }
    }

    const int tc = (t & 31) * 4;   // col base
    const int tr = (t >> 5) * 4;   // row base in tile
    float acc[4][4] = {};

    for (int chunk = 0; chunk < 2; ++chunk) {
        __syncthreads();
        // stage W chunk rows [chunk*64, chunk*64+64)
        {
            const float4* Wv = (const float4*)(W + (size_t)chunk * 64 * HH);
            float4* Wlv = (float4*)Wl;
            for (int i = t; i < 64 * (HH / 4); i += 256) Wlv[i] = Wv[i];
        }
        __syncthreads();
        const int kbase = chunk * 64;
#pragma unroll 8
        for (int k = 0; k < 64; ++k) {
            const float4 w = *(const float4*)&Wl[k * HH + tc];
            const int kk = kbase + k;
#pragma unroll
            for (int r = 0; r < 4; ++r) {
                const float a = Al[(tr + r) * HH + kk];
                acc[r][0] = fmaf(a, w.x, acc[r][0]);
                acc[r][1] = fmaf(a, w.y, acc[r][1]);
                acc[r][2] = fmaf(a, w.z, acc[r][2]);
                acc[r][3] = fmaf(a, w.w, acc[r][3]);
            }
        }
    }

#pragma unroll
    for (int r = 0; r < 4; ++r) {
        if (tr + r < rows_here) {
            const size_t row = (size_t)row0 + tr + r;
            float4 o = {acc[r][0], acc[r][1], acc[r][2], acc[r][3]};
            if (HAS_BIAS) {
                float ds = HAS_DEG ? (float)deg[row] : 1.0f;
                o.x += ds * bias[tc + 0];
                o.y += ds * bias[tc + 1];
                o.z += ds * bias[tc + 2];
                o.w += ds * bias[tc + 3];
            }
            if (HAS_CIN) {
                const float4 ci = *(const float4*)&Cin[row * HH + tc];
                o.x += ci.x; o.y += ci.y; o.z += ci.z; o.w += ci.w;
            }
            if (RELU) {
                o.x = fmaxf(o.x, 0.f); o.y = fmaxf(o.y, 0.f);
                o.z = fmaxf(o.z, 0.f); o.w = fmaxf(o.w, 0.f);
            }
            *(float4*)&Out[row * HH + tc] = o;
        }
    }
}

// ---------------- MP edge pass: outH[n] = sum_e leaky_relu(P[n]+Q[src_e]) (in-place on P OK)
__global__ void k_edge_mp(const float* __restrict__ P, const float* __restrict__ Q,
                          const int* __restrict__ offsets, const int* __restrict__ csrc,
                          float* __restrict__ outH) {
    const int n = blockIdx.x;
    const int j = threadIdx.x;
    const int beg = offsets[n], end = offsets[n + 1];
    const float p = P[(size_t)n * HH + j];
    float acc = 0.f;
    int i = beg;
    for (; i + 4 <= end; i += 4) {
        int s0 = csrc[i + 0], s1 = csrc[i + 1], s2 = csrc[i + 2], s3 = csrc[i + 3];
        float v0 = p + Q[(size_t)s0 * HH + j];
        float v1 = p + Q[(size_t)s1 * HH + j];
        float v2 = p + Q[(size_t)s2 * HH + j];
        float v3 = p + Q[(size_t)s3 * HH + j];
        v0 = (v0 > 0.f) ? v0 : 0.2f * v0;
        v1 = (v1 > 0.f) ? v1 : 0.2f * v1;
        v2 = (v2 > 0.f) ? v2 : 0.2f * v2;
        v3 = (v3 > 0.f) ? v3 : 0.2f * v3;
        acc += v0 + v1 + v2 + v3;
    }
    for (; i < end; ++i) {
        int s = csrc[i];
        float v = p + Q[(size_t)s * HH + j];
        acc += (v > 0.f) ? v : 0.2f * v;
    }
    outH[(size_t)n * HH + j] = acc;
}

// ---------------- SpMM: Y[n] = sum_e norm_e * X[src_e]
__global__ void k_spmm(const float* __restrict__ X, const int* __restrict__ offsets,
                       const int* __restrict__ csrc, const float* __restrict__ cnorm,
                       float* __restrict__ Y) {
    const int n = blockIdx.x;
    const int j = threadIdx.x;
    const int beg = offsets[n], end = offsets[n + 1];
    float acc = 0.f;
    int i = beg;
    for (; i + 4 <= end; i += 4) {
        int s0 = csrc[i + 0], s1 = csrc[i + 1], s2 = csrc[i + 2], s3 = csrc[i + 3];
        float n0 = cnorm[i + 0], n1 = cnorm[i + 1], n2 = cnorm[i + 2], n3 = cnorm[i + 3];
        acc += n0 * X[(size_t)s0 * HH + j] + n1 * X[(size_t)s1 * HH + j] +
               n2 * X[(size_t)s2 * HH + j] + n3 * X[(size_t)s3 * HH + j];
    }
    for (; i < end; ++i) acc += cnorm[i] * X[(size_t)csrc[i] * HH + j];
    Y[(size_t)n * HH + j] = acc;
}

extern "C" void kernel_launch(void* const* d_in, const int* in_sizes, int n_in,
                              void* d_out, int out_size, void* d_ws, size_t ws_size,
                              hipStream_t stream) {
    const float* x  = (const float*)d_in[0];
    const int*   ei = (const int*)d_in[1];
    const float* W1 = (const float*)d_in[2];
    const float* b1 = (const float*)d_in[3];
    const float* W2 = (const float*)d_in[4];
    const float* b2 = (const float*)d_in[5];
    const float* tw = (const float*)d_in[6];
    const float* tb = (const float*)d_in[7];
    float* out = (float*)d_out;

    const int* srcp = ei;
    const int* dstp = ei + NE;

    char* p = (char*)d_ws;
    auto alloc = [&](size_t bytes) { char* r = p; p += align256(bytes); return r; };
    int*   deg     = (int*)alloc((size_t)NN * 4);
    int*   cursor  = (int*)alloc((size_t)NN * 4);
    int*   offsets = (int*)alloc((size_t)(NN + 1) * 4);
    float* dinv    = (float*)alloc((size_t)NN * 4);
    int*   csrc    = (int*)alloc((size_t)NE * 4);
    float* cnorm   = (float*)alloc((size_t)NE * 4);
    float* P       = (float*)alloc((size_t)NN * HH * 4);
    float* Q       = (float*)alloc((size_t)NN * HH * 4);
    float* bufA    = (float*)alloc((size_t)NN * HH * 4);
    float* bufB    = (float*)alloc((size_t)NN * HH * 4);
    float* bufC    = (float*)alloc((size_t)NN * HH * 4);

    hipMemsetAsync(deg, 0, (size_t)NN * 4, stream);
    hipMemsetAsync(cursor, 0, (size_t)NN * 4, stream);

    k_deg<<<(NE + 255) / 256, 256, 0, stream>>>(dstp, deg);
    k_scan<<<1, 1024, 0, stream>>>(deg, offsets, dinv, NN);
    k_fill<<<(NE + 255) / 256, 256, 0, stream>>>(srcp, dstp, offsets, cursor, dinv, csrc, cnorm);

    const int mmgrid = (NN + 31) / 32;

    // MP layer: P = x@W1[:H] + b1 ; Q = x@W1[H:]
    k_mm<1, 0, 0, 0><<<mmgrid, 256, 0, stream>>>(x, W1, b1, nullptr, nullptr, P, NN);
    k_mm<0, 0, 0, 0><<<mmgrid, 256, 0, stream>>>(x, W1 + 128 * 128, nullptr, nullptr, nullptr, Q, NN);
    // H[n] = sum_e leaky_relu(P[n]+Q[s])   (in place over P)
    k_edge_mp<<<NN, HH, 0, stream>>>(P, Q, offsets, csrc, P);
    // x_mp = H@W2 + deg*b2 -> bufA
    k_mm<1, 1, 0, 0><<<mmgrid, 256, 0, stream>>>(P, W2, b2, deg, nullptr, bufA, NN);

    // 3 TAGConv layers, K_HOPS=3
    for (int L = 0; L < 3; ++L) {
        const float* Wt = tw + (size_t)L * 4 * 128 * 128;
        const float* bL = tb + (size_t)L * 128;
        // out = x@W0 + b  -> bufC
        k_mm<1, 0, 0, 0><<<mmgrid, 256, 0, stream>>>(bufA, Wt, bL, nullptr, nullptr, bufC, NN);
        // hop1: x1 = A_norm x  (bufA -> bufB); out += x1@W1
        k_spmm<<<NN, HH, 0, stream>>>(bufA, offsets, csrc, cnorm, bufB);
        k_mm<0, 0, 1, 0><<<mmgrid, 256, 0, stream>>>(bufB, Wt + 16384, nullptr, nullptr, bufC, bufC, NN);
        // hop2: x2 = A_norm x1 (bufB -> bufA); out += x2@W2
        k_spmm<<<NN, HH, 0, stream>>>(bufB, offsets, csrc, cnorm, bufA);
        k_mm<0, 0, 1, 0><<<mmgrid, 256, 0, stream>>>(bufA, Wt + 2 * 16384, nullptr, nullptr, bufC, bufC, NN);
        // hop3: x3 = A_norm x2 (bufA -> bufB); out += x3@W3, relu, write next-layer input
        k_spmm<<<NN, HH, 0, stream>>>(bufA, offsets, csrc, cnorm, bufB);
        float* dest = (L == 2) ? out : bufA;
        k_mm<0, 0, 1, 1><<<mmgrid, 256, 0, stream>>>(bufB, Wt + 3 * 16384, nullptr, nullptr, bufC, dest, NN);
    }
}

// Round 2
// 1115.969 us; speedup vs baseline: 1.1292x; 1.1292x over previous
//
#include <hip/hip_runtime.h>

#define NN 50000
#define NE 800000
#define HH 128
#define SCAN_BLK 256
#define NBLK ((NN + SCAN_BLK - 1) / SCAN_BLK)   // 196

static inline size_t align256(size_t x) { return (x + 255) & ~(size_t)255; }

// ---------------- degree histogram ----------------
__global__ void k_deg(const int* __restrict__ dst, int* __restrict__ deg) {
    int e = blockIdx.x * 256 + threadIdx.x;
    if (e < NE) atomicAdd(&deg[dst[e]], 1);
}

// ---------------- two-level scan ----------------
__global__ void k_bsum(const int* __restrict__ deg, int* __restrict__ part) {
    __shared__ int sd[SCAN_BLK];
    int t = threadIdx.x;
    int i = blockIdx.x * SCAN_BLK + t;
    sd[t] = (i < NN) ? deg[i] : 0;
    __syncthreads();
    for (int off = SCAN_BLK / 2; off > 0; off >>= 1) {
        if (t < off) sd[t] += sd[t + off];
        __syncthreads();
    }
    if (t == 0) part[blockIdx.x] = sd[0];
}

__global__ void k_scanpart(const int* __restrict__ part, int* __restrict__ partoff) {
    __shared__ int sd[SCAN_BLK];
    int t = threadIdx.x;
    int v = (t < NBLK) ? part[t] : 0;
    sd[t] = v;
    __syncthreads();
    for (int off = 1; off < SCAN_BLK; off <<= 1) {
        int add = (t >= off) ? sd[t - off] : 0;
        __syncthreads();
        sd[t] += add;
        __syncthreads();
    }
    if (t < NBLK) partoff[t] = sd[t] - v;
}

__global__ void k_apply(const int* __restrict__ deg, const int* __restrict__ partoff,
                        int* __restrict__ offsets, float* __restrict__ dinv) {
    __shared__ int sd[SCAN_BLK];
    int t = threadIdx.x;
    int i = blockIdx.x * SCAN_BLK + t;
    int v = (i < NN) ? deg[i] : 0;
    sd[t] = v;
    __syncthreads();
    for (int off = 1; off < SCAN_BLK; off <<= 1) {
        int add = (t >= off) ? sd[t - off] : 0;
        __syncthreads();
        sd[t] += add;
        __syncthreads();
    }
    if (i < NN) {
        offsets[i] = partoff[blockIdx.x] + sd[t] - v;
        dinv[i] = (v > 0) ? rsqrtf((float)v) : 0.0f;
    }
    if (i == 0) offsets[NN] = NE;
}

// ---------------- CSR fill (sorted by dst) ----------------
__global__ void k_fill(const int* __restrict__ src, const int* __restrict__ dst,
                       const int* __restrict__ offsets, int* __restrict__ cursor,
                       const float* __restrict__ dinv,
                       int* __restrict__ csrc, float* __restrict__ cnorm) {
    int e = blockIdx.x * 256 + threadIdx.x;
    if (e >= NE) return;
    int s = src[e], d = dst[e];
    int pos = atomicAdd(&cursor[d], 1);
    int idx = offsets[d] + pos;
    csrc[idx] = s;
    cnorm[idx] = dinv[s] * dinv[d];
}

// ---------------- dense matmul: Out[n][0:128] = A[n][0:KDIM]@W + bias(*deg) (relu?)
// A row stride lda, Out row stride ldo. 32 rows x 128 cols per block, K chunked by 64.
template <int KDIM, int HAS_BIAS, int HAS_DEG, int RELU>
__global__ __launch_bounds__(256) void k_mm(
    const float* __restrict__ A, int lda,
    const float* __restrict__ W,
    const float* __restrict__ bias, const int* __restrict__ deg,
    float* __restrict__ Out, int ldo, int nrows) {
    __shared__ float Wl[64 * HH];   // 32 KB: K-chunk of W
    __shared__ float Al[32 * 64];   // 8 KB: 32-row x 64-K tile of A
    const int t = threadIdx.x;
    const int row0 = blockIdx.x * 32;
    const int rows_here = min(32, nrows - row0);
    const int tc = (t & 31) * 4;   // col base 0..124
    const int tr = (t >> 5) * 4;   // row base 0..28
    float acc[4][4] = {};

    constexpr int NCH = KDIM / 64;
    for (int c = 0; c < NCH; ++c) {
        __syncthreads();
        // stage W rows [c*64, c*64+64)
        {
            const float4* Wv = (const float4*)(W + (size_t)c * 64 * HH);
            float4* Wlv = (float4*)Wl;
            for (int i = t; i < 64 * (HH / 4); i += 256) Wlv[i] = Wv[i];
        }
        // stage A tile cols [c*64, c*64+64)
        {
            float4* Alv = (float4*)Al;
            for (int i = t; i < 512; i += 256) {
                int r = i >> 4, q = i & 15;
                float4 z = {0.f, 0.f, 0.f, 0.f};
                Alv[i] = (r < rows_here)
                    ? *(const float4*)&A[(size_t)(row0 + r) * lda + c * 64 + q * 4] : z;
            }
        }
        __syncthreads();
#pragma unroll
        for (int k4 = 0; k4 < 16; ++k4) {
            const float4 w0 = *(const float4*)&Wl[(k4 * 4 + 0) * HH + tc];
            const float4 w1 = *(const float4*)&Wl[(k4 * 4 + 1) * HH + tc];
            const float4 w2 = *(const float4*)&Wl[(k4 * 4 + 2) * HH + tc];
            const float4 w3 = *(const float4*)&Wl[(k4 * 4 + 3) * HH + tc];
#pragma unroll
            for (int r = 0; r < 4; ++r) {
                const float4 a = *(const float4*)&Al[(tr + r) * 64 + k4 * 4];
                acc[r][0] = fmaf(a.x, w0.x, fmaf(a.y, w1.x, fmaf(a.z, w2.x, fmaf(a.w, w3.x, acc[r][0]))));
                acc[r][1] = fmaf(a.x, w0.y, fmaf(a.y, w1.y, fmaf(a.z, w2.y, fmaf(a.w, w3.y, acc[r][1]))));
                acc[r][2] = fmaf(a.x, w0.z, fmaf(a.y, w1.z, fmaf(a.z, w2.z, fmaf(a.w, w3.z, acc[r][2]))));
                acc[r][3] = fmaf(a.x, w0.w, fmaf(a.y, w1.w, fmaf(a.z, w2.w, fmaf(a.w, w3.w, acc[r][3]))));
            }
        }
    }

#pragma unroll
    for (int r = 0; r < 4; ++r) {
        if (tr + r < rows_here) {
            const size_t row = (size_t)row0 + tr + r;
            float4 o = {acc[r][0], acc[r][1], acc[r][2], acc[r][3]};
            if (HAS_BIAS) {
                float ds = HAS_DEG ? (float)deg[row] : 1.0f;
                o.x += ds * bias[tc + 0];
                o.y += ds * bias[tc + 1];
                o.z += ds * bias[tc + 2];
                o.w += ds * bias[tc + 3];
            }
            if (RELU) {
                o.x = fmaxf(o.x, 0.f); o.y = fmaxf(o.y, 0.f);
                o.z = fmaxf(o.z, 0.f); o.w = fmaxf(o.w, 0.f);
            }
            *(float4*)&Out[row * ldo + tc] = o;
        }
    }
}

// ---------------- MP edge pass over PQ[N,256]: H[n][j] = sum_e lrelu(PQ[n][j] + PQ[s][128+j])
// writes H into PQ[n][j] (cols 0:128; gathers only touch cols 128:256 -> safe)
__global__ void k_edge_mp(float* __restrict__ PQ, const int* __restrict__ offsets,
                          const int* __restrict__ csrc) {
    const int n = blockIdx.x;
    const int j = threadIdx.x;
    const int beg = offsets[n], end = offsets[n + 1];
    const float p = PQ[(size_t)n * 256 + j];
    float acc = 0.f;
    int i = beg;
    for (; i + 4 <= end; i += 4) {
        int s0 = csrc[i + 0], s1 = csrc[i + 1], s2 = csrc[i + 2], s3 = csrc[i + 3];
        float v0 = p + PQ[(size_t)s0 * 256 + 128 + j];
        float v1 = p + PQ[(size_t)s1 * 256 + 128 + j];
        float v2 = p + PQ[(size_t)s2 * 256 + 128 + j];
        float v3 = p + PQ[(size_t)s3 * 256 + 128 + j];
        v0 = (v0 > 0.f) ? v0 : 0.2f * v0;
        v1 = (v1 > 0.f) ? v1 : 0.2f * v1;
        v2 = (v2 > 0.f) ? v2 : 0.2f * v2;
        v3 = (v3 > 0.f) ? v3 : 0.2f * v3;
        acc += v0 + v1 + v2 + v3;
    }
    for (; i < end; ++i) {
        int s = csrc[i];
        float v = p + PQ[(size_t)s * 256 + 128 + j];
        acc += (v > 0.f) ? v : 0.2f * v;
    }
    PQ[(size_t)n * 256 + j] = acc;
}

// ---------------- SpMM over X4[N,512]: Y-col-block[n][j] = sum_e norm_e * X-col-block[src_e][j]
__global__ void k_spmm(const float* __restrict__ Xin, float* __restrict__ Yout,
                       const int* __restrict__ offsets, const int* __restrict__ csrc,
                       const float* __restrict__ cnorm) {
    const int n = blockIdx.x;
    const int j = threadIdx.x;
    const int beg = offsets[n], end = offsets[n + 1];
    float acc = 0.f;
    int i = beg;
    for (; i + 4 <= end; i += 4) {
        int s0 = csrc[i + 0], s1 = csrc[i + 1], s2 = csrc[i + 2], s3 = csrc[i + 3];
        float n0 = cnorm[i + 0], n1 = cnorm[i + 1], n2 = cnorm[i + 2], n3 = cnorm[i + 3];
        acc += n0 * Xin[(size_t)s0 * 512 + j] + n1 * Xin[(size_t)s1 * 512 + j] +
               n2 * Xin[(size_t)s2 * 512 + j] + n3 * Xin[(size_t)s3 * 512 + j];
    }
    for (; i < end; ++i) acc += cnorm[i] * Xin[(size_t)csrc[i] * 512 + j];
    Yout[(size_t)n * 512 + j] = acc;
}

extern "C" void kernel_launch(void* const* d_in, const int* in_sizes, int n_in,
                              void* d_out, int out_size, void* d_ws, size_t ws_size,
                              hipStream_t stream) {
    const float* x  = (const float*)d_in[0];
    const int*   ei = (const int*)d_in[1];
    const float* W1 = (const float*)d_in[2];
    const float* b1 = (const float*)d_in[3];
    const float* W2 = (const float*)d_in[4];
    const float* b2 = (const float*)d_in[5];
    const float* tw = (const float*)d_in[6];
    const float* tb = (const float*)d_in[7];
    float* out = (float*)d_out;

    const int* srcp = ei;
    const int* dstp = ei + NE;

    char* p = (char*)d_ws;
    auto alloc = [&](size_t bytes) { char* r = p; p += align256(bytes); return r; };
    int*   deg     = (int*)alloc((size_t)NN * 4);
    int*   cursor  = (int*)alloc((size_t)NN * 4);
    int*   offsets = (int*)alloc((size_t)(NN + 1) * 4);
    float* dinv    = (float*)alloc((size_t)NN * 4);
    int*   part    = (int*)alloc((size_t)NBLK * 4);
    int*   partoff = (int*)alloc((size_t)NBLK * 4);
    int*   csrc    = (int*)alloc((size_t)NE * 4);
    float* cnorm   = (float*)alloc((size_t)NE * 4);
    float* PQ      = (float*)alloc((size_t)NN * 256 * 4);   // [N,256]: P|Q, later H|Q
    float* X4      = (float*)alloc((size_t)NN * 512 * 4);   // [N,512]: x0|x1|x2|x3

    hipMemsetAsync(deg, 0, (size_t)NN * 4, stream);
    hipMemsetAsync(cursor, 0, (size_t)NN * 4, stream);

    k_deg<<<(NE + 255) / 256, 256, 0, stream>>>(dstp, deg);
    k_bsum<<<NBLK, SCAN_BLK, 0, stream>>>(deg, part);
    k_scanpart<<<1, SCAN_BLK, 0, stream>>>(part, partoff);
    k_apply<<<NBLK, SCAN_BLK, 0, stream>>>(deg, partoff, offsets, dinv);
    k_fill<<<(NE + 255) / 256, 256, 0, stream>>>(srcp, dstp, offsets, cursor, dinv, csrc, cnorm);

    const int mmgrid = (NN + 31) / 32;

    // MP layer: PQ[:,0:128] = x@W1[:128]+b1 ; PQ[:,128:256] = x@W1[128:]
    k_mm<128, 1, 0, 0><<<mmgrid, 256, 0, stream>>>(x, HH, W1, b1, nullptr, PQ, 256, NN);
    k_mm<128, 0, 0, 0><<<mmgrid, 256, 0, stream>>>(x, HH, W1 + 128 * 128, nullptr, nullptr, PQ + 128, 256, NN);
    // H[n] = sum_e lrelu(P[n]+Q[s]) -> PQ cols 0:128
    k_edge_mp<<<NN, HH, 0, stream>>>(PQ, offsets, csrc);
    // x0 = H@W2 + deg*b2 -> X4 cols 0:128
    k_mm<128, 1, 1, 0><<<mmgrid, 256, 0, stream>>>(PQ, 256, W2, b2, deg, X4, 512, NN);

    // 3 TAGConv layers: x_{k} = A_norm x_{k-1} into col blocks, then one wide GEMM
    for (int L = 0; L < 3; ++L) {
        const float* Wt = tw + (size_t)L * 4 * 128 * 128;   // [512][128] stacked
        const float* bL = tb + (size_t)L * 128;
        k_spmm<<<NN, HH, 0, stream>>>(X4 + 0,   X4 + 128, offsets, csrc, cnorm);
        k_spmm<<<NN, HH, 0, stream>>>(X4 + 128, X4 + 256, offsets, csrc, cnorm);
        k_spmm<<<NN, HH, 0, stream>>>(X4 + 256, X4 + 384, offsets, csrc, cnorm);
        if (L < 2) {
            k_mm<512, 1, 0, 1><<<mmgrid, 256, 0, stream>>>(X4, 512, Wt, bL, nullptr, X4, 512, NN);
        } else {
            k_mm<512, 1, 0, 1><<<mmgrid, 256, 0, stream>>>(X4, 512, Wt, bL, nullptr, out, HH, NN);
        }
    }
}

// Round 3
// 575.562 us; speedup vs baseline: 2.1894x; 1.9389x over previous
//
#include <hip/hip_runtime.h>

#define NN 50000
#define NE 800000
#define HH 128
#define SCAN_BLK 256
#define NBLK ((NN + SCAN_BLK - 1) / SCAN_BLK)   // 196

typedef _Float16 half8 __attribute__((ext_vector_type(8)));
typedef _Float16 half4 __attribute__((ext_vector_type(4)));
typedef _Float16 half2t __attribute__((ext_vector_type(2)));
typedef float floatx16 __attribute__((ext_vector_type(16)));

static inline size_t align256(size_t x) { return (x + 255) & ~(size_t)255; }

// ---------------- degree histogram ----------------
__global__ void k_deg(const int* __restrict__ dst, int* __restrict__ deg) {
    int e = blockIdx.x * 256 + threadIdx.x;
    if (e < NE) atomicAdd(&deg[dst[e]], 1);
}

// ---------------- two-level scan ----------------
__global__ void k_bsum(const int* __restrict__ deg, int* __restrict__ part) {
    __shared__ int sd[SCAN_BLK];
    int t = threadIdx.x;
    int i = blockIdx.x * SCAN_BLK + t;
    sd[t] = (i < NN) ? deg[i] : 0;
    __syncthreads();
    for (int off = SCAN_BLK / 2; off > 0; off >>= 1) {
        if (t < off) sd[t] += sd[t + off];
        __syncthreads();
    }
    if (t == 0) part[blockIdx.x] = sd[0];
}

__global__ void k_scanpart(const int* __restrict__ part, int* __restrict__ partoff) {
    __shared__ int sd[SCAN_BLK];
    int t = threadIdx.x;
    int v = (t < NBLK) ? part[t] : 0;
    sd[t] = v;
    __syncthreads();
    for (int off = 1; off < SCAN_BLK; off <<= 1) {
        int add = (t >= off) ? sd[t - off] : 0;
        __syncthreads();
        sd[t] += add;
        __syncthreads();
    }
    if (t < NBLK) partoff[t] = sd[t] - v;
}

__global__ void k_apply(const int* __restrict__ deg, const int* __restrict__ partoff,
                        int* __restrict__ offsets, float* __restrict__ dinv) {
    __shared__ int sd[SCAN_BLK];
    int t = threadIdx.x;
    int i = blockIdx.x * SCAN_BLK + t;
    int v = (i < NN) ? deg[i] : 0;
    sd[t] = v;
    __syncthreads();
    for (int off = 1; off < SCAN_BLK; off <<= 1) {
        int add = (t >= off) ? sd[t - off] : 0;
        __syncthreads();
        sd[t] += add;
        __syncthreads();
    }
    if (i < NN) {
        offsets[i] = partoff[blockIdx.x] + sd[t] - v;
        dinv[i] = (v > 0) ? rsqrtf((float)v) : 0.0f;
    }
    if (i == 0) offsets[NN] = NE;
}

// ---------------- CSR fill (sorted by dst) ----------------
__global__ void k_fill(const int* __restrict__ src, const int* __restrict__ dst,
                       const int* __restrict__ offsets, int* __restrict__ cursor,
                       const float* __restrict__ dinv,
                       int* __restrict__ csrc, float* __restrict__ cnorm) {
    int e = blockIdx.x * 256 + threadIdx.x;
    if (e >= NE) return;
    int s = src[e], d = dst[e];
    int pos = atomicAdd(&cursor[d], 1);
    int idx = offsets[d] + pos;
    csrc[idx] = s;
    cnorm[idx] = dinv[s] * dinv[d];
}

// ---------------- convert x to fp16 ----------------
__global__ void k_cvt_x(const float* __restrict__ x, _Float16* __restrict__ xh) {
    int i = blockIdx.x * 256 + threadIdx.x;
    if (i * 4 < NN * HH) {
        float4 v = *(const float4*)(x + (size_t)i * 4);
        half4 h;
        h.x = (_Float16)v.x; h.y = (_Float16)v.y;
        h.z = (_Float16)v.z; h.w = (_Float16)v.w;
        *(half4*)(xh + (size_t)i * 4) = h;
    }
}

// ---------------- convert + transpose weights to fp16 k-major ----------------
// W1tP[c][k]=W1[k][c]; W1tQ[c][k]=W1[128+k][c]; W2t[c][k]=W2[k][c];
// TWt[L][c][k]=tw[L][k>>7][k&127][c]   (k in 0..511)
__global__ void k_cvt_w(const float* __restrict__ W1, const float* __restrict__ W2,
                        const float* __restrict__ tw,
                        _Float16* __restrict__ W1tP, _Float16* __restrict__ W1tQ,
                        _Float16* __restrict__ W2t, _Float16* __restrict__ TWt) {
    int i = blockIdx.x * 256 + threadIdx.x;
    if (i < 16384) {
        int c = i >> 7, k = i & 127;
        W1tP[c * 128 + k] = (_Float16)W1[k * 128 + c];
        W1tQ[c * 128 + k] = (_Float16)W1[(128 + k) * 128 + c];
    } else if (i < 32768) {
        int j = i - 16384;
        int c = j >> 7, k = j & 127;
        W2t[c * 128 + k] = (_Float16)W2[k * 128 + c];
    } else if (i < 32768 + 3 * 65536) {
        int j = i - 32768;
        int L = j >> 16;
        int c = (j >> 9) & 127;
        int k = j & 511;
        TWt[(size_t)L * 65536 + c * 512 + k] =
            (_Float16)tw[(size_t)L * 65536 + (size_t)(k >> 7) * 16384 + (size_t)(k & 127) * 128 + c];
    }
}

// ---------------- MFMA GEMM: Out[n][0:128] = A[n][0:KDIM] @ W + bias(*deg) (relu?)
// A: fp16 [nrows][lda]. Bt: fp16 [128 cols][KDIM] (k-major). Out: OutT, stride ldo.
// Block: 128 rows x 128 cols, 4 waves each 64x64 (2x2 frags of 32x32), K chunk 64.
template <int KDIM, int HAS_BIAS, int HAS_DEG, int RELU, typename OutT>
__global__ __launch_bounds__(256) void k_mm(
    const _Float16* __restrict__ A, int lda,
    const _Float16* __restrict__ Bt,
    const float* __restrict__ bias, const int* __restrict__ deg,
    OutT* __restrict__ Out, int ldo, int nrows) {
    __shared__ _Float16 As[128 * 64];   // 16 KB, XOR-swizzled rows of 128B
    __shared__ _Float16 Bs[128 * 64];   // 16 KB
    const int t = threadIdx.x;
    const int l = t & 63;
    const int w = t >> 6;
    const int wm = w >> 1, wn = w & 1;
    const int row0 = blockIdx.x * 128;

    floatx16 acc[2][2] = {};

    const int srow = t >> 3;   // 0..31
    const int sslot = t & 7;   // 16B slot in 128B row

    for (int c = 0; c < KDIM / 64; ++c) {
        __syncthreads();
#pragma unroll
        for (int p = 0; p < 4; ++p) {
            int r = srow + p * 32;
            int g = row0 + r;
            uint4 v = make_uint4(0, 0, 0, 0);
            if (g < nrows) v = *(const uint4*)(A + (size_t)g * lda + c * 64 + sslot * 8);
            *(uint4*)((char*)As + r * 128 + ((sslot * 16) ^ ((r & 7) << 4))) = v;
        }
#pragma unroll
        for (int p = 0; p < 4; ++p) {
            int r = srow + p * 32;
            uint4 v = *(const uint4*)(Bt + (size_t)r * KDIM + c * 64 + sslot * 8);
            *(uint4*)((char*)Bs + r * 128 + ((sslot * 16) ^ ((r & 7) << 4))) = v;
        }
        __syncthreads();
#pragma unroll
        for (int ks = 0; ks < 4; ++ks) {
            const int koff = ks * 32 + (l >> 5) * 16;   // byte offset of 8-half frag
            half8 a0, a1, b0, b1;
            { int r = wm * 64 + (l & 31);      a0 = *(const half8*)((const char*)As + r * 128 + (koff ^ ((r & 7) << 4))); }
            { int r = wm * 64 + 32 + (l & 31); a1 = *(const half8*)((const char*)As + r * 128 + (koff ^ ((r & 7) << 4))); }
            { int r = wn * 64 + (l & 31);      b0 = *(const half8*)((const char*)Bs + r * 128 + (koff ^ ((r & 7) << 4))); }
            { int r = wn * 64 + 32 + (l & 31); b1 = *(const half8*)((const char*)Bs + r * 128 + (koff ^ ((r & 7) << 4))); }
            acc[0][0] = __builtin_amdgcn_mfma_f32_32x32x16_f16(a0, b0, acc[0][0], 0, 0, 0);
            acc[0][1] = __builtin_amdgcn_mfma_f32_32x32x16_f16(a0, b1, acc[0][1], 0, 0, 0);
            acc[1][0] = __builtin_amdgcn_mfma_f32_32x32x16_f16(a1, b0, acc[1][0], 0, 0, 0);
            acc[1][1] = __builtin_amdgcn_mfma_f32_32x32x16_f16(a1, b1, acc[1][1], 0, 0, 0);
        }
    }

#pragma unroll
    for (int mf = 0; mf < 2; ++mf) {
#pragma unroll
        for (int nf = 0; nf < 2; ++nf) {
            const int col = wn * 64 + nf * 32 + (l & 31);
            const float bc = HAS_BIAS ? bias[col] : 0.0f;
#pragma unroll
            for (int r = 0; r < 16; ++r) {
                int row = wm * 64 + mf * 32 + 4 * (l >> 5) + (r & 3) + 8 * (r >> 2);
                int g = row0 + row;
                if (g < nrows) {
                    float v = acc[mf][nf][r];
                    if (HAS_BIAS) v += (HAS_DEG ? (float)deg[g] : 1.0f) * bc;
                    if (RELU) v = fmaxf(v, 0.0f);
                    Out[(size_t)g * ldo + col] = (OutT)v;
                }
            }
        }
    }
}

// ---------------- MP edge pass over PQ[N,256] fp16:
// H[n][j] = sum_e lrelu(P[n][j] + Q[src][j]); writes into cols 0:128 (gathers cols 128:256)
__global__ void k_edge_mp(_Float16* __restrict__ PQ, const int* __restrict__ offsets,
                          const int* __restrict__ csrc) {
    const int n = blockIdx.x;
    const int j = threadIdx.x;          // 0..63, cols 2j,2j+1
    const int beg = offsets[n], end = offsets[n + 1];
    half2t p2 = *(const half2t*)(PQ + (size_t)n * 256 + 2 * j);
    const float p0 = (float)p2.x, p1 = (float)p2.y;
    float a0 = 0.f, a1 = 0.f;
    int i = beg;
    for (; i + 2 <= end; i += 2) {
        int s0 = csrc[i], s1 = csrc[i + 1];
        half2t q0 = *(const half2t*)(PQ + (size_t)s0 * 256 + 128 + 2 * j);
        half2t q1 = *(const half2t*)(PQ + (size_t)s1 * 256 + 128 + 2 * j);
        float v00 = p0 + (float)q0.x, v01 = p1 + (float)q0.y;
        float v10 = p0 + (float)q1.x, v11 = p1 + (float)q1.y;
        a0 += ((v00 > 0.f) ? v00 : 0.2f * v00) + ((v10 > 0.f) ? v10 : 0.2f * v10);
        a1 += ((v01 > 0.f) ? v01 : 0.2f * v01) + ((v11 > 0.f) ? v11 : 0.2f * v11);
    }
    if (i < end) {
        int s = csrc[i];
        half2t q = *(const half2t*)(PQ + (size_t)s * 256 + 128 + 2 * j);
        float v0 = p0 + (float)q.x, v1 = p1 + (float)q.y;
        a0 += (v0 > 0.f) ? v0 : 0.2f * v0;
        a1 += (v1 > 0.f) ? v1 : 0.2f * v1;
    }
    half2t o; o.x = (_Float16)a0; o.y = (_Float16)a1;
    *(half2t*)(PQ + (size_t)n * 256 + 2 * j) = o;
}

// ---------------- SpMM fp16 over X4[N,512] col blocks: Y[n][j] = sum_e norm_e * X[src][j]
__global__ void k_spmm(const _Float16* __restrict__ Xin, _Float16* __restrict__ Yout,
                       const int* __restrict__ offsets, const int* __restrict__ csrc,
                       const float* __restrict__ cnorm) {
    const int n = blockIdx.x;
    const int j = threadIdx.x;          // 0..63, cols 2j,2j+1
    const int beg = offsets[n], end = offsets[n + 1];
    float a0 = 0.f, a1 = 0.f;
    int i = beg;
    for (; i + 2 <= end; i += 2) {
        int s0 = csrc[i], s1 = csrc[i + 1];
        float n0 = cnorm[i], n1 = cnorm[i + 1];
        half2t v0 = *(const half2t*)(Xin + (size_t)s0 * 512 + 2 * j);
        half2t v1 = *(const half2t*)(Xin + (size_t)s1 * 512 + 2 * j);
        a0 += n0 * (float)v0.x + n1 * (float)v1.x;
        a1 += n0 * (float)v0.y + n1 * (float)v1.y;
    }
    if (i < end) {
        int s = csrc[i];
        float nv = cnorm[i];
        half2t v = *(const half2t*)(Xin + (size_t)s * 512 + 2 * j);
        a0 += nv * (float)v.x;
        a1 += nv * (float)v.y;
    }
    half2t o; o.x = (_Float16)a0; o.y = (_Float16)a1;
    *(half2t*)(Yout + (size_t)n * 512 + 2 * j) = o;
}

extern "C" void kernel_launch(void* const* d_in, const int* in_sizes, int n_in,
                              void* d_out, int out_size, void* d_ws, size_t ws_size,
                              hipStream_t stream) {
    const float* x  = (const float*)d_in[0];
    const int*   ei = (const int*)d_in[1];
    const float* W1 = (const float*)d_in[2];
    const float* b1 = (const float*)d_in[3];
    const float* W2 = (const float*)d_in[4];
    const float* b2 = (const float*)d_in[5];
    const float* tw = (const float*)d_in[6];
    const float* tb = (const float*)d_in[7];
    float* out = (float*)d_out;

    const int* srcp = ei;
    const int* dstp = ei + NE;

    char* p = (char*)d_ws;
    auto alloc = [&](size_t bytes) { char* r = p; p += align256(bytes); return r; };
    int*       deg     = (int*)alloc((size_t)NN * 4);
    int*       cursor  = (int*)alloc((size_t)NN * 4);
    int*       offsets = (int*)alloc((size_t)(NN + 1) * 4);
    float*     dinv    = (float*)alloc((size_t)NN * 4);
    int*       part    = (int*)alloc((size_t)NBLK * 4);
    int*       partoff = (int*)alloc((size_t)NBLK * 4);
    int*       csrc    = (int*)alloc((size_t)NE * 4);
    float*     cnorm   = (float*)alloc((size_t)NE * 4);
    _Float16*  xh      = (_Float16*)alloc((size_t)NN * HH * 2);
    _Float16*  PQ      = (_Float16*)alloc((size_t)NN * 256 * 2);
    _Float16*  X4      = (_Float16*)alloc((size_t)NN * 512 * 2);
    _Float16*  W1tP    = (_Float16*)alloc(16384 * 2);
    _Float16*  W1tQ    = (_Float16*)alloc(16384 * 2);
    _Float16*  W2t     = (_Float16*)alloc(16384 * 2);
    _Float16*  TWt     = (_Float16*)alloc((size_t)3 * 65536 * 2);

    hipMemsetAsync(deg, 0, (size_t)NN * 4, stream);
    hipMemsetAsync(cursor, 0, (size_t)NN * 4, stream);

    k_deg<<<(NE + 255) / 256, 256, 0, stream>>>(dstp, deg);
    k_bsum<<<NBLK, SCAN_BLK, 0, stream>>>(deg, part);
    k_scanpart<<<1, SCAN_BLK, 0, stream>>>(part, partoff);
    k_apply<<<NBLK, SCAN_BLK, 0, stream>>>(deg, partoff, offsets, dinv);
    k_fill<<<(NE + 255) / 256, 256, 0, stream>>>(srcp, dstp, offsets, cursor, dinv, csrc, cnorm);

    k_cvt_x<<<(NN * HH / 4 + 255) / 256, 256, 0, stream>>>(x, xh);
    k_cvt_w<<<(32768 + 3 * 65536 + 255) / 256, 256, 0, stream>>>(W1, W2, tw, W1tP, W1tQ, W2t, TWt);

    const int mmgrid = (NN + 127) / 128;

    // MP layer: P = x@W1[:128]+b1 -> PQ[:,0:128]; Q = x@W1[128:] -> PQ[:,128:256]
    k_mm<128, 1, 0, 0, _Float16><<<mmgrid, 256, 0, stream>>>(xh, HH, W1tP, b1, nullptr, PQ, 256, NN);
    k_mm<128, 0, 0, 0, _Float16><<<mmgrid, 256, 0, stream>>>(xh, HH, W1tQ, nullptr, nullptr, PQ + 128, 256, NN);
    // H[n] = sum_e lrelu(P[n]+Q[s]) -> PQ cols 0:128
    k_edge_mp<<<NN, 64, 0, stream>>>(PQ, offsets, csrc);
    // x0 = H@W2 + deg*b2 -> X4 cols 0:128
    k_mm<128, 1, 1, 0, _Float16><<<mmgrid, 256, 0, stream>>>(PQ, 256, W2t, b2, deg, X4, 512, NN);

    // 3 TAGConv layers: 3 hops into col blocks, then one wide [N,512]@[512,128] GEMM
    for (int L = 0; L < 3; ++L) {
        const _Float16* Wt = TWt + (size_t)L * 65536;
        const float* bL = tb + (size_t)L * 128;
        k_spmm<<<NN, 64, 0, stream>>>(X4 + 0,   X4 + 128, offsets, csrc, cnorm);
        k_spmm<<<NN, 64, 0, stream>>>(X4 + 128, X4 + 256, offsets, csrc, cnorm);
        k_spmm<<<NN, 64, 0, stream>>>(X4 + 256, X4 + 384, offsets, csrc, cnorm);
        if (L < 2) {
            k_mm<512, 1, 0, 1, _Float16><<<mmgrid, 256, 0, stream>>>(X4, 512, Wt, bL, nullptr, X4, 512, NN);
        } else {
            k_mm<512, 1, 0, 1, float><<<mmgrid, 256, 0, stream>>>(X4, 512, Wt, bL, nullptr, out, HH, NN);
        }
    }
}

// Round 4
// 529.406 us; speedup vs baseline: 2.3803x; 1.0872x over previous
//
#include <hip/hip_runtime.h>

#define NN 50000
#define NE 800000
#define HH 128
#define SCAN_BLK 256
#define NBLK ((NN + SCAN_BLK - 1) / SCAN_BLK)   // 196
#define NB8 ((NN + 7) / 8)                      // 6250

typedef _Float16 half8 __attribute__((ext_vector_type(8)));
typedef _Float16 half4 __attribute__((ext_vector_type(4)));
typedef float floatx16 __attribute__((ext_vector_type(16)));

static inline size_t align256(size_t x) { return (x + 255) & ~(size_t)255; }

// ---------------- degree histogram ----------------
__global__ void k_deg(const int* __restrict__ dst, int* __restrict__ deg) {
    int e = blockIdx.x * 256 + threadIdx.x;
    if (e < NE) atomicAdd(&deg[dst[e]], 1);
}

// ---------------- two-level scan ----------------
__global__ void k_bsum(const int* __restrict__ deg, int* __restrict__ part) {
    __shared__ int sd[SCAN_BLK];
    int t = threadIdx.x;
    int i = blockIdx.x * SCAN_BLK + t;
    sd[t] = (i < NN) ? deg[i] : 0;
    __syncthreads();
    for (int off = SCAN_BLK / 2; off > 0; off >>= 1) {
        if (t < off) sd[t] += sd[t + off];
        __syncthreads();
    }
    if (t == 0) part[blockIdx.x] = sd[0];
}

__global__ void k_scanpart(const int* __restrict__ part, int* __restrict__ partoff) {
    __shared__ int sd[SCAN_BLK];
    int t = threadIdx.x;
    int v = (t < NBLK) ? part[t] : 0;
    sd[t] = v;
    __syncthreads();
    for (int off = 1; off < SCAN_BLK; off <<= 1) {
        int add = (t >= off) ? sd[t - off] : 0;
        __syncthreads();
        sd[t] += add;
        __syncthreads();
    }
    if (t < NBLK) partoff[t] = sd[t] - v;
}

__global__ void k_apply(const int* __restrict__ deg, const int* __restrict__ partoff,
                        int* __restrict__ offsets, float* __restrict__ dinv) {
    __shared__ int sd[SCAN_BLK];
    int t = threadIdx.x;
    int i = blockIdx.x * SCAN_BLK + t;
    int v = (i < NN) ? deg[i] : 0;
    sd[t] = v;
    __syncthreads();
    for (int off = 1; off < SCAN_BLK; off <<= 1) {
        int add = (t >= off) ? sd[t - off] : 0;
        __syncthreads();
        sd[t] += add;
        __syncthreads();
    }
    if (i < NN) {
        offsets[i] = partoff[blockIdx.x] + sd[t] - v;
        dinv[i] = (v > 0) ? rsqrtf((float)v) : 0.0f;
    }
    if (i == 0) offsets[NN] = NE;
}

// ---------------- CSR fill (sorted by dst), packed (src, norm) records ----------------
__global__ void k_fill(const int* __restrict__ src, const int* __restrict__ dst,
                       const int* __restrict__ offsets, int* __restrict__ cursor,
                       const float* __restrict__ dinv, uint2* __restrict__ epk) {
    int e = blockIdx.x * 256 + threadIdx.x;
    if (e >= NE) return;
    int s = src[e], d = dst[e];
    int pos = atomicAdd(&cursor[d], 1);
    int idx = offsets[d] + pos;
    float nv = dinv[s] * dinv[d];
    epk[idx] = make_uint2((unsigned)s, __float_as_uint(nv));
}

// ---------------- convert x to fp16 ----------------
__global__ void k_cvt_x(const float* __restrict__ x, _Float16* __restrict__ xh) {
    int i = blockIdx.x * 256 + threadIdx.x;
    if (i * 4 < NN * HH) {
        float4 v = *(const float4*)(x + (size_t)i * 4);
        half4 h;
        h.x = (_Float16)v.x; h.y = (_Float16)v.y;
        h.z = (_Float16)v.z; h.w = (_Float16)v.w;
        *(half4*)(xh + (size_t)i * 4) = h;
    }
}

// ---------------- convert + transpose weights to fp16 k-major ----------------
__global__ void k_cvt_w(const float* __restrict__ W1, const float* __restrict__ W2,
                        const float* __restrict__ tw,
                        _Float16* __restrict__ W1tP, _Float16* __restrict__ W1tQ,
                        _Float16* __restrict__ W2t, _Float16* __restrict__ TWt) {
    int i = blockIdx.x * 256 + threadIdx.x;
    if (i < 16384) {
        int c = i >> 7, k = i & 127;
        W1tP[c * 128 + k] = (_Float16)W1[k * 128 + c];
        W1tQ[c * 128 + k] = (_Float16)W1[(128 + k) * 128 + c];
    } else if (i < 32768) {
        int j = i - 16384;
        int c = j >> 7, k = j & 127;
        W2t[c * 128 + k] = (_Float16)W2[k * 128 + c];
    } else if (i < 32768 + 3 * 65536) {
        int j = i - 32768;
        int L = j >> 16;
        int c = (j >> 9) & 127;
        int k = j & 511;
        TWt[(size_t)L * 65536 + c * 512 + k] =
            (_Float16)tw[(size_t)L * 65536 + (size_t)(k >> 7) * 16384 + (size_t)(k & 127) * 128 + c];
    }
}

// ---------------- MFMA GEMM (unchanged from round 3) ----------------
template <int KDIM, int HAS_BIAS, int HAS_DEG, int RELU, typename OutT>
__global__ __launch_bounds__(256) void k_mm(
    const _Float16* __restrict__ A, int lda,
    const _Float16* __restrict__ Bt,
    const float* __restrict__ bias, const int* __restrict__ deg,
    OutT* __restrict__ Out, int ldo, int nrows) {
    __shared__ _Float16 As[128 * 64];
    __shared__ _Float16 Bs[128 * 64];
    const int t = threadIdx.x;
    const int l = t & 63;
    const int w = t >> 6;
    const int wm = w >> 1, wn = w & 1;
    const int row0 = blockIdx.x * 128;

    floatx16 acc[2][2] = {};

    const int srow = t >> 3;
    const int sslot = t & 7;

    for (int c = 0; c < KDIM / 64; ++c) {
        __syncthreads();
#pragma unroll
        for (int p = 0; p < 4; ++p) {
            int r = srow + p * 32;
            int g = row0 + r;
            uint4 v = make_uint4(0, 0, 0, 0);
            if (g < nrows) v = *(const uint4*)(A + (size_t)g * lda + c * 64 + sslot * 8);
            *(uint4*)((char*)As + r * 128 + ((sslot * 16) ^ ((r & 7) << 4))) = v;
        }
#pragma unroll
        for (int p = 0; p < 4; ++p) {
            int r = srow + p * 32;
            uint4 v = *(const uint4*)(Bt + (size_t)r * KDIM + c * 64 + sslot * 8);
            *(uint4*)((char*)Bs + r * 128 + ((sslot * 16) ^ ((r & 7) << 4))) = v;
        }
        __syncthreads();
#pragma unroll
        for (int ks = 0; ks < 4; ++ks) {
            const int koff = ks * 32 + (l >> 5) * 16;
            half8 a0, a1, b0, b1;
            { int r = wm * 64 + (l & 31);      a0 = *(const half8*)((const char*)As + r * 128 + (koff ^ ((r & 7) << 4))); }
            { int r = wm * 64 + 32 + (l & 31); a1 = *(const half8*)((const char*)As + r * 128 + (koff ^ ((r & 7) << 4))); }
            { int r = wn * 64 + (l & 31);      b0 = *(const half8*)((const char*)Bs + r * 128 + (koff ^ ((r & 7) << 4))); }
            { int r = wn * 64 + 32 + (l & 31); b1 = *(const half8*)((const char*)Bs + r * 128 + (koff ^ ((r & 7) << 4))); }
            acc[0][0] = __builtin_amdgcn_mfma_f32_32x32x16_f16(a0, b0, acc[0][0], 0, 0, 0);
            acc[0][1] = __builtin_amdgcn_mfma_f32_32x32x16_f16(a0, b1, acc[0][1], 0, 0, 0);
            acc[1][0] = __builtin_amdgcn_mfma_f32_32x32x16_f16(a1, b0, acc[1][0], 0, 0, 0);
            acc[1][1] = __builtin_amdgcn_mfma_f32_32x32x16_f16(a1, b1, acc[1][1], 0, 0, 0);
        }
    }

#pragma unroll
    for (int mf = 0; mf < 2; ++mf) {
#pragma unroll
        for (int nf = 0; nf < 2; ++nf) {
            const int col = wn * 64 + nf * 32 + (l & 31);
            const float bc = HAS_BIAS ? bias[col] : 0.0f;
#pragma unroll
            for (int r = 0; r < 16; ++r) {
                int row = wm * 64 + mf * 32 + 4 * (l >> 5) + (r & 3) + 8 * (r >> 2);
                int g = row0 + row;
                if (g < nrows) {
                    float v = acc[mf][nf][r];
                    if (HAS_BIAS) v += (HAS_DEG ? (float)deg[g] : 1.0f) * bc;
                    if (RELU) v = fmaxf(v, 0.0f);
                    Out[(size_t)g * ldo + col] = (OutT)v;
                }
            }
        }
    }
}

// ---------------- MP edge pass, 8 nodes/block (32 lanes x half4 each) ----------------
// H[n][j] = sum_e lrelu(P[n][j] + Q[src][j]); in-place cols 0:128 (gathers cols 128:256)
__global__ __launch_bounds__(256) void k_edge_mp(_Float16* __restrict__ PQ,
                                                 const int* __restrict__ offsets,
                                                 const uint2* __restrict__ epk) {
    const int t = threadIdx.x;
    const int n = blockIdx.x * 8 + (t >> 5);
    if (n >= NN) return;
    const int lane = t & 31;
    const int beg = offsets[n], end = offsets[n + 1];
    half4 p4 = *(const half4*)(PQ + (size_t)n * 256 + lane * 4);
    const float p0 = (float)p4.x, p1 = (float)p4.y, p2 = (float)p4.z, p3 = (float)p4.w;
    float a0 = 0.f, a1 = 0.f, a2 = 0.f, a3 = 0.f;
    int i = beg;
#define LRELU4(vx, vy, vz, vw)                                        \
    a0 += ((vx) > 0.f) ? (vx) : 0.2f * (vx);                          \
    a1 += ((vy) > 0.f) ? (vy) : 0.2f * (vy);                          \
    a2 += ((vz) > 0.f) ? (vz) : 0.2f * (vz);                          \
    a3 += ((vw) > 0.f) ? (vw) : 0.2f * (vw);
    for (; i + 4 <= end; i += 4) {
        uint2 e0 = epk[i + 0], e1 = epk[i + 1], e2 = epk[i + 2], e3 = epk[i + 3];
        half4 q0 = *(const half4*)(PQ + (size_t)e0.x * 256 + 128 + lane * 4);
        half4 q1 = *(const half4*)(PQ + (size_t)e1.x * 256 + 128 + lane * 4);
        half4 q2 = *(const half4*)(PQ + (size_t)e2.x * 256 + 128 + lane * 4);
        half4 q3 = *(const half4*)(PQ + (size_t)e3.x * 256 + 128 + lane * 4);
        LRELU4(p0 + (float)q0.x, p1 + (float)q0.y, p2 + (float)q0.z, p3 + (float)q0.w)
        LRELU4(p0 + (float)q1.x, p1 + (float)q1.y, p2 + (float)q1.z, p3 + (float)q1.w)
        LRELU4(p0 + (float)q2.x, p1 + (float)q2.y, p2 + (float)q2.z, p3 + (float)q2.w)
        LRELU4(p0 + (float)q3.x, p1 + (float)q3.y, p2 + (float)q3.z, p3 + (float)q3.w)
    }
    for (; i < end; ++i) {
        uint2 e = epk[i];
        half4 q = *(const half4*)(PQ + (size_t)e.x * 256 + 128 + lane * 4);
        LRELU4(p0 + (float)q.x, p1 + (float)q.y, p2 + (float)q.z, p3 + (float)q.w)
    }
#undef LRELU4
    half4 o;
    o.x = (_Float16)a0; o.y = (_Float16)a1; o.z = (_Float16)a2; o.w = (_Float16)a3;
    *(half4*)(PQ + (size_t)n * 256 + lane * 4) = o;
}

// ---------------- SpMM, 8 nodes/block (32 lanes x half4), X4 stride 512 ----------------
__global__ __launch_bounds__(256) void k_spmm(const _Float16* __restrict__ Xin,
                                              _Float16* __restrict__ Yout,
                                              const int* __restrict__ offsets,
                                              const uint2* __restrict__ epk) {
    const int t = threadIdx.x;
    const int n = blockIdx.x * 8 + (t >> 5);
    if (n >= NN) return;
    const int lane = t & 31;
    const int beg = offsets[n], end = offsets[n + 1];
    float a0 = 0.f, a1 = 0.f, a2 = 0.f, a3 = 0.f;
    int i = beg;
    for (; i + 4 <= end; i += 4) {
        uint2 e0 = epk[i + 0], e1 = epk[i + 1], e2 = epk[i + 2], e3 = epk[i + 3];
        half4 v0 = *(const half4*)(Xin + (size_t)e0.x * 512 + lane * 4);
        half4 v1 = *(const half4*)(Xin + (size_t)e1.x * 512 + lane * 4);
        half4 v2 = *(const half4*)(Xin + (size_t)e2.x * 512 + lane * 4);
        half4 v3 = *(const half4*)(Xin + (size_t)e3.x * 512 + lane * 4);
        float n0 = __uint_as_float(e0.y), n1 = __uint_as_float(e1.y);
        float n2 = __uint_as_float(e2.y), n3 = __uint_as_float(e3.y);
        a0 += n0 * (float)v0.x + n1 * (float)v1.x + n2 * (float)v2.x + n3 * (float)v3.x;
        a1 += n0 * (float)v0.y + n1 * (float)v1.y + n2 * (float)v2.y + n3 * (float)v3.y;
        a2 += n0 * (float)v0.z + n1 * (float)v1.z + n2 * (float)v2.z + n3 * (float)v3.z;
        a3 += n0 * (float)v0.w + n1 * (float)v1.w + n2 * (float)v2.w + n3 * (float)v3.w;
    }
    for (; i < end; ++i) {
        uint2 e = epk[i];
        float nv = __uint_as_float(e.y);
        half4 v = *(const half4*)(Xin + (size_t)e.x * 512 + lane * 4);
        a0 += nv * (float)v.x; a1 += nv * (float)v.y;
        a2 += nv * (float)v.z; a3 += nv * (float)v.w;
    }
    half4 o;
    o.x = (_Float16)a0; o.y = (_Float16)a1; o.z = (_Float16)a2; o.w = (_Float16)a3;
    *(half4*)(Yout + (size_t)n * 512 + lane * 4) = o;
}

extern "C" void kernel_launch(void* const* d_in, const int* in_sizes, int n_in,
                              void* d_out, int out_size, void* d_ws, size_t ws_size,
                              hipStream_t stream) {
    const float* x  = (const float*)d_in[0];
    const int*   ei = (const int*)d_in[1];
    const float* W1 = (const float*)d_in[2];
    const float* b1 = (const float*)d_in[3];
    const float* W2 = (const float*)d_in[4];
    const float* b2 = (const float*)d_in[5];
    const float* tw = (const float*)d_in[6];
    const float* tb = (const float*)d_in[7];
    float* out = (float*)d_out;

    const int* srcp = ei;
    const int* dstp = ei + NE;

    char* p = (char*)d_ws;
    auto alloc = [&](size_t bytes) { char* r = p; p += align256(bytes); return r; };
    int*       deg     = (int*)alloc((size_t)NN * 4);
    int*       cursor  = (int*)alloc((size_t)NN * 4);
    int*       offsets = (int*)alloc((size_t)(NN + 1) * 4);
    float*     dinv    = (float*)alloc((size_t)NN * 4);
    int*       part    = (int*)alloc((size_t)NBLK * 4);
    int*       partoff = (int*)alloc((size_t)NBLK * 4);
    uint2*     epk     = (uint2*)alloc((size_t)NE * 8);
    _Float16*  xh      = (_Float16*)alloc((size_t)NN * HH * 2);
    _Float16*  PQ      = (_Float16*)alloc((size_t)NN * 256 * 2);
    _Float16*  X4      = (_Float16*)alloc((size_t)NN * 512 * 2);
    _Float16*  W1tP    = (_Float16*)alloc(16384 * 2);
    _Float16*  W1tQ    = (_Float16*)alloc(16384 * 2);
    _Float16*  W2t     = (_Float16*)alloc(16384 * 2);
    _Float16*  TWt     = (_Float16*)alloc((size_t)3 * 65536 * 2);

    hipMemsetAsync(deg, 0, (size_t)NN * 4, stream);
    hipMemsetAsync(cursor, 0, (size_t)NN * 4, stream);

    k_deg<<<(NE + 255) / 256, 256, 0, stream>>>(dstp, deg);
    k_bsum<<<NBLK, SCAN_BLK, 0, stream>>>(deg, part);
    k_scanpart<<<1, SCAN_BLK, 0, stream>>>(part, partoff);
    k_apply<<<NBLK, SCAN_BLK, 0, stream>>>(deg, partoff, offsets, dinv);
    k_fill<<<(NE + 255) / 256, 256, 0, stream>>>(srcp, dstp, offsets, cursor, dinv, epk);

    k_cvt_x<<<(NN * HH / 4 + 255) / 256, 256, 0, stream>>>(x, xh);
    k_cvt_w<<<(32768 + 3 * 65536 + 255) / 256, 256, 0, stream>>>(W1, W2, tw, W1tP, W1tQ, W2t, TWt);

    const int mmgrid = (NN + 127) / 128;

    // MP layer
    k_mm<128, 1, 0, 0, _Float16><<<mmgrid, 256, 0, stream>>>(xh, HH, W1tP, b1, nullptr, PQ, 256, NN);
    k_mm<128, 0, 0, 0, _Float16><<<mmgrid, 256, 0, stream>>>(xh, HH, W1tQ, nullptr, nullptr, PQ + 128, 256, NN);
    k_edge_mp<<<NB8, 256, 0, stream>>>(PQ, offsets, epk);
    k_mm<128, 1, 1, 0, _Float16><<<mmgrid, 256, 0, stream>>>(PQ, 256, W2t, b2, deg, X4, 512, NN);

    // 3 TAGConv layers
    for (int L = 0; L < 3; ++L) {
        const _Float16* Wt = TWt + (size_t)L * 65536;
        const float* bL = tb + (size_t)L * 128;
        k_spmm<<<NB8, 256, 0, stream>>>(X4 + 0,   X4 + 128, offsets, epk);
        k_spmm<<<NB8, 256, 0, stream>>>(X4 + 128, X4 + 256, offsets, epk);
        k_spmm<<<NB8, 256, 0, stream>>>(X4 + 256, X4 + 384, offsets, epk);
        if (L < 2) {
            k_mm<512, 1, 0, 1, _Float16><<<mmgrid, 256, 0, stream>>>(X4, 512, Wt, bL, nullptr, X4, 512, NN);
        } else {
            k_mm<512, 1, 0, 1, float><<<mmgrid, 256, 0, stream>>>(X4, 512, Wt, bL, nullptr, out, HH, NN);
        }
    }
}